// Round 5
// baseline (5220.559 us; speedup 1.0000x reference)
//
#include <hip/hip_runtime.h>
#include <hip/hip_bf16.h>
#include <stdint.h>

// RNNPB via per-step MFMA GEMM (R16 = R15 + own-frag early-read + rotated chains).
// Invariant across R11-R15: MFMA-busy ~398 cyc-equiv/step/CU (MfmaUtil x step)
// while step varied 1043-1243 -> residual is serial overhead, chiefly the
// post-barrier ds_read->MFMA bubble (~120 cyc of MFMA-pipe idle).
// Key fact: wave w writes EXACTLY frag w of the next panel (tiles 2w,2w+1 =
// rows [32w,32w+32) = k-frag w) for w=0..6. So each wave (w<7):
//   ... h-writes ... s_waitcnt lgkmcnt(0) ; ds_read OWN frag of buf[nxt] ;
//   s_barrier   -> the read completes inside the barrier-wait shadow.
// The MFMA chain is ROTATED per wave (template<W0>, switch on scalar w) to
// start at frag w (register-resident at barrier exit); the other 7 reads
// issue in rotated order = consumption order. Wave 7 (frag 7 shared with
// d-feed) keeps the unrotated pattern. w via readfirstlane -> scalar branches.
//   h_{t+1} = relu(M h_t + W1d d_{t+1} + cb' + W1p pb),  out_t = W2d h_t + b2d
// A (f16, 256x256): rows [0,240) h, [240,246) out (W2d); cols [0,240) M/W2d,
//   [240,246) W1d, 246 bias, 247/248 W1p, 249+ zero.
// B panel frag-major: Hx[buf][frag 0..7][lane 0..63][8 halves]; element (k,n):
//   frag k>>5, lane ((k&31)>>3)*16+n, sub k&7. Lane-contiguous b128 reads.
// 2 blocks x 16 batches; 8 waves (2/SIMD) x 2 row-tiles x 8 K-frags.
// d-input via 96-lane register FIFO (waves 0-1): one 2B L2-hot load per step.

#define T_STEPS 8192
#define HID     240
#define CTX     180
#define KTOT    256
#define HXBUF   4096                       // halves/buffer: 8 frags x 64 lanes x 8
#define A_HALVES (256*256)
#define SCRATCH_BYTES (A_HALVES*2 + 16)

typedef __hip_bfloat16 bf16;
typedef _Float16 f16;
typedef _Float16 half8  __attribute__((ext_vector_type(8)));
typedef _Float16 half4v __attribute__((ext_vector_type(4)));
typedef float    f32x4  __attribute__((ext_vector_type(4)));
typedef float    f32x2  __attribute__((ext_vector_type(2)));

#define MFMA16(A,B,C) __builtin_amdgcn_mfma_f32_16x16x32_f16((A),(B),(C),0,0,0)

__device__ __forceinline__ float ldin(const void* p, long i, bool f32) {
    return f32 ? ((const float*)p)[i] : __bfloat162float(((const bf16*)p)[i]);
}
__device__ __forceinline__ unsigned pkbf(float a, float b) {
    unsigned ua = (unsigned)__builtin_bit_cast(unsigned short, __float2bfloat16(a));
    unsigned ub = (unsigned)__builtin_bit_cast(unsigned short, __float2bfloat16(b));
    return ua | (ub << 16);
}

// deferred out-store: writes the 6 outputs of one step (wave 7, quads 0-1)
__device__ __forceinline__ void store_out(void* out, bool f32, int quad, long ob, f32x4 v) {
    if (quad == 0) {                                   // out elems 0..3
        if (!f32) {
            bf16* op = (bf16*)out + ob;
            *(unsigned*)(op)     = pkbf(v.x, v.y);
            *(unsigned*)(op + 2) = pkbf(v.z, v.w);
        } else {
            float* op = (float*)out + ob;
            f32x2 p0 = {v.x, v.y}; *(f32x2*)(op)     = p0;
            f32x2 p1 = {v.z, v.w}; *(f32x2*)(op + 2) = p1;
        }
    } else if (quad == 1) {                            // out elems 4,5
        if (!f32) {
            bf16* op = (bf16*)out + ob;
            *(unsigned*)(op + 4) = pkbf(v.x, v.y);
        } else {
            float* op = (float*)out + ob;
            f32x2 p0 = {v.x, v.y}; *(f32x2*)(op + 4) = p0;
        }
    }
}

// rotated B-frag reads: issue order W0+1,..,W0+7 (EARLY) so arrival order
// matches consumption order; b[W0] comes from the pre-barrier early read.
template<int W0, bool EARLY>
__device__ __forceinline__ void rot_read(const f16* hxc, half8 b[8], half8 be) {
    #pragma unroll
    for (int j = EARLY ? 1 : 0; j < 8; ++j) {
        const int f = (W0 + j) & 7;
        b[f] = *(const half8*)(hxc + f*512);
    }
    if (EARLY) b[W0] = be;
}

// rotated MFMA chains: c0 consumes frags W0..W0+7, c1 consumes W0+1..W0+7
// (its final MFMA, on b[W0], is done by the caller so the c0 epilogue overlaps).
template<int W0>
__device__ __forceinline__ void rot_mfma(const half8 A0[8], const half8 A1[8],
                                         const half8 b[8], f32x4& c0, f32x4& c1,
                                         half8& lastA, half8& lastB) {
    #pragma unroll
    for (int j = 0; j < 8; ++j) {
        const int f0 = (W0 + j) & 7;
        c0 = MFMA16(A0[f0], b[f0], c0);
        if (j < 7) {
            const int f1 = (W0 + 1 + j) & 7;
            c1 = MFMA16(A1[f1], b[f1], c1);
        }
    }
    lastA = A1[W0]; lastB = b[W0];
}

// fp32 arrays: low half-words are random mantissa (huge-as-bf16 w.p. ~0.45/word)
// or all-zero (bf16-grid). Real bf16 arrays: neither. (Verified R2-R10: bf16 path.)
__global__ __launch_bounds__(64) void detect_dtype(const void* data, int* flag) {
    unsigned int w  = ((const unsigned int*)data)[threadIdx.x];
    unsigned int lo = w & 0xFFFFu;
    unsigned int ex = (lo >> 7) & 0xFFu;
    unsigned long long huge = __ballot(ex >= 0x8Eu);
    unsigned long long zero = __ballot(lo == 0u);
    if (threadIdx.x == 0) *flag = (huge != 0ull || zero == ~0ull) ? 1 : 0;
}

// ---------------- build augmented A (f16) ----------------
__global__ __launch_bounds__(256) void build_A(
    const void* __restrict__ W1d, const void* __restrict__ b1d,
    const void* __restrict__ W1p, const void* __restrict__ b1p,
    const void* __restrict__ W1c, const void* __restrict__ b1c,
    const void* __restrict__ W2d, const void* __restrict__ b2d,
    const void* __restrict__ W2c, const void* __restrict__ b2c,
    f16* __restrict__ Aa, const int* __restrict__ flagp)
{
    const bool f32 = (*flagp != 0);
    int idx = blockIdx.x*256 + threadIdx.x;
    int r = idx >> 8, k = idx & 255;
    float v = 0.f;
    if (r < HID) {
        if (k < HID) {                           // M = W1c @ W2c
            float acc = 0.f;
            for (int c = 0; c < CTX; ++c)
                acc = fmaf(ldin(W1c, r*CTX+c, f32), ldin(W2c, c*HID+k, f32), acc);
            v = acc;
        } else if (k < 246) {                    // W1d columns
            v = ldin(W1d, r*6 + (k-240), f32);
        } else if (k == 246) {                   // bias: b1d+b1c+b1p + W1c@b2c
            float m0 = 0.f;
            for (int c = 0; c < CTX; ++c)
                m0 = fmaf(ldin(W1c, r*CTX+c, f32), ldin(b2c, c, f32), m0);
            v = ldin(b1d, r, f32) + ldin(b1c, r, f32) + ldin(b1p, r, f32) + m0;
        } else if (k <= 248) {                   // W1p columns
            v = ldin(W1p, r*2 + (k-247), f32);
        }
    } else if (r < 246) {                        // out rows
        int o = r - 240;
        if (k < HID)       v = ldin(W2d, o*HID + k, f32);
        else if (k == 246) v = ldin(b2d, o, f32);
    }
    Aa[idx] = (f16)v;
}

// frag-major Hx offset for scalar element (row j, col n), within one buffer
__device__ __forceinline__ int hx_off(int j, int n) {
    return (j >> 5)*512 + ((((j & 31) >> 3))*16 + n)*8 + (j & 7);
}

// ---------------- per-step MFMA recurrent kernel: 2 blocks x 16 batches ----------------
__global__ __launch_bounds__(512, 2) void rnn_mfma(
    const void* __restrict__ data,   // [30][6][8192]
    const void* __restrict__ b1d, const void* __restrict__ W1p,
    const void* __restrict__ b1p, const void* __restrict__ b1c,
    const void* __restrict__ W1d, const void* __restrict__ pb,
    const f16* __restrict__ Aa, const int* __restrict__ flagp,
    void* __restrict__ out)          // [30][8192][6]
{
    const bool f32 = (*flagp != 0);
    const int tid  = threadIdx.x;
    const int w    = __builtin_amdgcn_readfirstlane(tid >> 6);  // scalar wave id
    const int l    = tid & 63;
    const int n16  = l & 15;
    const int quad = l >> 4;
    const int base = blockIdx.x * 16;
    const int bn   = base + n16;
    const bool bvalid = (bn < 30);
    const long obase = (long)bn * T_STEPS * 6;

    __shared__ __align__(16) f16 Hx[2*HXBUF];        // 16,384 B

    // ---- zero Hx (rows >248 and untouched slots must stay 0)
    {
        int* hz = (int*)Hx;
        for (int i = tid; i < HXBUF; i += 512) hz[i] = 0;    // 4096 ints = both buffers
    }
    __syncthreads();

    // ---- const rows 246/247/248 in both buffers
    // row246 -> frag7,quad'2,j'6 ; row247 -> frag7,quad'2,j'7 ; row248 -> frag7,quad'3,j'0
    if (tid < 32) {
        int bsel = tid >> 4, n = tid & 15;
        int nb = base + n; if (nb > 29) nb = 29;
        f16* buf = Hx + bsel*HXBUF;
        buf[3584 + (32+n)*8 + 6] = (f16)1.0f;
        buf[3584 + (32+n)*8 + 7] = (f16)ldin(pb, nb*2+0, f32);
        buf[3584 + (48+n)*8 + 0] = (f16)ldin(pb, nb*2+1, f32);
    }

    // ---- h_0 = relu(cb + W1d d_0)  into Hx[0]
    for (int p = tid; p < HID*16; p += 512) {
        int n = p / HID, j = p - n*HID;
        int nb = base + n; if (nb > 29) nb = 29;
        float s = ldin(b1d, j, f32) + ldin(b1c, j, f32) + ldin(b1p, j, f32)
                + ldin(W1p, j*2+0, f32)*ldin(pb, nb*2+0, f32)
                + ldin(W1p, j*2+1, f32)*ldin(pb, nb*2+1, f32);
        for (int d = 0; d < 6; ++d)
            s = fmaf(ldin(W1d, j*6+d, f32), ldin(data, ((long)nb*6+d)*T_STEPS, f32), s);
        Hx[hx_off(j, n)] = (f16)fmaxf(s, 0.f);
    }

    // ---- d-feed lane roles (tid<96 = waves 0-1): (pn, pd)
    const int pn = tid & 15, pd = tid >> 4;
    int pnb = base + pn; if (pnb > 29) pnb = 29;
    const long prow = ((long)pnb*6 + (pd < 6 ? pd : 0))*T_STEPS;
    const int  doff = 3584 + (32+pn)*8 + pd;     // row (240+pd), col pn

    // d_1 into Hx[0] rows 240..245
    if (tid < 96)
        Hx[doff] = (f16)ldin(data, prow + 1, f32);

    // d-FIFO preload: u0 = raw d[2] (consumed step 0), u1 = raw d[3] (step 1)
    unsigned u0 = 0, u1 = 0;
    const unsigned esz = f32 ? 4u : 2u;
    unsigned voff = (unsigned)((unsigned long)(prow + 4) * esz);           // d[t+4] @ t=0
    const unsigned vmax = (unsigned)((unsigned long)(prow + T_STEPS-1) * esz);
    if (tid < 96) {
        if (!f32) {
            u0 = ((const unsigned short*)data)[prow + 2];
            u1 = ((const unsigned short*)data)[prow + 3];
        } else {
            u0 = __builtin_bit_cast(unsigned, ((const float*)data)[prow + 2]);
            u1 = __builtin_bit_cast(unsigned, ((const float*)data)[prow + 3]);
        }
    }

    // ---- persistent A fragments as constexpr-indexed arrays (register-resident)
    const f16* Ab0 = Aa + (size_t)((w*2+0)*16 + n16)*KTOT + quad*8;
    const f16* Ab1 = Aa + (size_t)((w*2+1)*16 + n16)*KTOT + quad*8;
    half8 A0[8], A1[8];
    #pragma unroll
    for (int j = 0; j < 8; ++j) {
        A0[j] = *(const half8*)(Ab0 + j*32);
        A1[j] = *(const half8*)(Ab1 + j*32);
    }
    // drain A reads before any wave can store into the (possible) d_out-tail scratch
    asm volatile("s_waitcnt vmcnt(0)" ::: "memory");
    __syncthreads();

    // ---- steady-state addressing
    const f16* hxread0 = Hx + l*8;                   // panel base (lane-contiguous)
    const f16* hxro    = Hx + w*512 + l*8;           // OWN frag base (early read)
    // write: tile 2w at off0, tile 2w+1 at off0+256 (buffer select = +nxt*HXBUF)
    f16* hxw = Hx + w*512 + ((quad>>1)*16 + n16)*8 + 4*(quad&1);

    f32x4 pend = {0.f, 0.f, 0.f, 0.f};           // wave7: out values awaiting store
    half8 b_e = *(const half8*)(hxro);           // pre-loop: own frag of buf[0]

    for (int t2 = 0; t2 < T_STEPS; t2 += 2) {
        #pragma unroll
        for (int s = 0; s < 2; ++s) {
            const int t = t2 + s;
            const int cur = s, nxt = s ^ 1;      // compile-time parity

            // ---- (1) rotated B reads: 7 frags (own frag already in b_e)
            const f16* hxc = hxread0 + cur*HXBUF;
            half8 b[8];
            switch (w) {
                case 0: rot_read<0,true>(hxc, b, b_e); break;
                case 1: rot_read<1,true>(hxc, b, b_e); break;
                case 2: rot_read<2,true>(hxc, b, b_e); break;
                case 3: rot_read<3,true>(hxc, b, b_e); break;
                case 4: rot_read<4,true>(hxc, b, b_e); break;
                case 5: rot_read<5,true>(hxc, b, b_e); break;
                case 6: rot_read<6,true>(hxc, b, b_e); break;
                default: rot_read<0,false>(hxc, b, b_e); break;
            }

            // ---- (2) bubble fill: deferred out-store for step t-1 (wave 7)
            if (w == 7 && bvalid && (s == 1 || t2 > 0))
                store_out(out, f32, quad, obase + (long)(t-1)*6, pend);

            // ---- bubble fill: d-feed (waves 0-1): d_{t+2} -> Hx[nxt]; load d[t+4]
            if (tid < 96) {
                unsigned uc = (s == 0) ? u0 : u1;
                float dv = f32 ? __builtin_bit_cast(float, uc)
                               : __builtin_bit_cast(float, uc << 16);
                Hx[nxt*HXBUF + doff] = (f16)dv;
                unsigned un;
                if (!f32) un = *(const unsigned short*)((const char*)data + voff);
                else      un = __builtin_bit_cast(unsigned, *(const float*)((const char*)data + voff));
                unsigned vn = voff + esz;
                voff = (vn > vmax) ? vmax : vn;
                if (s == 0) u0 = un; else u1 = un;
            }

            // ---- (3) rotated MFMA chains: c0 starts on the register-resident frag
            f32x4 c0 = {0.f,0.f,0.f,0.f}, c1 = {0.f,0.f,0.f,0.f};
            half8 lastA, lastB;
            switch (w) {
                case 0: rot_mfma<0>(A0, A1, b, c0, c1, lastA, lastB); break;
                case 1: rot_mfma<1>(A0, A1, b, c0, c1, lastA, lastB); break;
                case 2: rot_mfma<2>(A0, A1, b, c0, c1, lastA, lastB); break;
                case 3: rot_mfma<3>(A0, A1, b, c0, c1, lastA, lastB); break;
                case 4: rot_mfma<4>(A0, A1, b, c0, c1, lastA, lastB); break;
                case 5: rot_mfma<5>(A0, A1, b, c0, c1, lastA, lastB); break;
                case 6: rot_mfma<6>(A0, A1, b, c0, c1, lastA, lastB); break;
                default: rot_mfma<0>(A0, A1, b, c0, c1, lastA, lastB); break;
            }

            // ---- epilogue c0 (tile 2w, always h): overlaps c1's last MFMA
            f16* hxn = hxw + nxt*HXBUF;
            {
                half4v hv;
                hv.x = (f16)fmaxf(c0.x, 0.f);
                hv.y = (f16)fmaxf(c0.y, 0.f);
                hv.z = (f16)fmaxf(c0.z, 0.f);
                hv.w = (f16)fmaxf(c0.w, 0.f);
                *(half4v*)(hxn) = hv;
            }
            c1 = MFMA16(lastA, lastB, c1);       // c1's final (rotated) MFMA

            // ---- epilogue c1: h-tile for waves 0-6; wave 7 defers out to t+1
            if (w < 7) {                         // tile 2w+1: h-tile
                half4v hv;
                hv.x = (f16)fmaxf(c1.x, 0.f);
                hv.y = (f16)fmaxf(c1.y, 0.f);
                hv.z = (f16)fmaxf(c1.z, 0.f);
                hv.w = (f16)fmaxf(c1.w, 0.f);
                *(half4v*)(hxn + 256) = hv;
            } else {
                pend = c1;                       // stored in next step's bubble
            }

            // ---- tail: drain my LDS writes; EARLY-READ own frag of buf[nxt]
            // (legal: frag w contains only rows I wrote, now drained); barrier.
            asm volatile("s_waitcnt lgkmcnt(0)" ::: "memory");
            if (w < 7)
                b_e = *(const half8*)(hxro + nxt*HXBUF);
            asm volatile("s_barrier" ::: "memory");
        }
    }

    // ---- final flush: out for t = T_STEPS-1
    if (w == 7 && bvalid)
        store_out(out, f32, quad, obase + (long)(T_STEPS-1)*6, pend);
}

extern "C" void kernel_launch(void* const* d_in, const int* in_sizes, int n_in,
                              void* d_out, int out_size, void* d_ws, size_t ws_size,
                              hipStream_t stream) {
    const void* data = d_in[0];
    const void* W1d  = d_in[1];
    const void* b1d  = d_in[2];
    const void* W1p  = d_in[3];
    const void* b1p  = d_in[4];
    const void* W1c  = d_in[5];
    const void* b1c  = d_in[6];
    const void* W2d  = d_in[7];
    const void* b2d  = d_in[8];
    const void* W2c  = d_in[9];
    const void* b2c  = d_in[10];
    const void* pb   = d_in[11];

    size_t need = SCRATCH_BYTES;
    char* scratch;
    if (ws_size >= need) {
        scratch = (char*)d_ws;
    } else {
        size_t out_bytes = (size_t)30*T_STEPS*6*sizeof(bf16);
        scratch = (char*)d_out + ((out_bytes - need) & ~(size_t)255);
    }
    f16* Aa    = (f16*)scratch;
    int* flagp = (int*)(scratch + A_HALVES*2);

    detect_dtype<<<1, 64, 0, stream>>>(data, flagp);
    build_A<<<A_HALVES/256, 256, 0, stream>>>(W1d, b1d, W1p, b1p, W1c, b1c,
                                              W2d, b2d, W2c, b2c, Aa, flagp);
    rnn_mfma<<<2, 512, 0, stream>>>(data, b1d, W1p, b1p, b1c, W1d, pb,
                                    Aa, flagp, d_out);
}

// Round 6
// 3780.895 us; speedup vs baseline: 1.3808x; 1.3808x over previous
//
#include <hip/hip_runtime.h>
#include <hip/hip_bf16.h>
#include <stdint.h>

// RNNPB via per-step MFMA GEMM (R17 = R15 + DATA-rotated chains + own-frag early-read).
// R16 lesson: switch<W0> rotation duplicated the hot body 8x -> I-cache thrash
// (MfmaUtil AND VALUBusy both fell). R17 delivers the same rotation through
// pointers/register contents with ONE loop body:
//   rot = (w<7)?w:0;  read ptr rp[j] = Hx + l*8 + ((rot+j)&7)*512;
//   A0r[j]/A1r[j] loaded pre-rotated from Aa.  Chain consumes j=0..7 uniformly.
// Wave w (w<7) wrote exactly frag w of buf[nxt] (tiles 2w,2w+1 = rows
// [32w,32w+32)), so after lgkmcnt(0) it ds_reads its OWN frag pre-barrier
// (b_e) = rotated j=0 -> first MFMA issues at barrier exit, no ~120cyc bubble.
// Wave 7 (frag 7 holds d-feed rows written in the same inter-barrier window -
// racy to early-read) keeps rot=0, no early read.
// Keeps R15: reads-first, deferred wave7 out-store, d-feed bubble fill,
// c1-tail MFMA after c0 epilogue, incremental 32-bit d voffset.
//   h_{t+1} = relu(M h_t + W1d d_{t+1} + cb' + W1p pb),  out_t = W2d h_t + b2d
// A (f16, 256x256): rows [0,240) h, [240,246) out (W2d); cols [0,240) M/W2d,
//   [240,246) W1d, 246 bias, 247/248 W1p, 249+ zero.
// B panel frag-major: Hx[buf][frag 0..7][lane 0..63][8 halves]; element (k,n):
//   frag k>>5, lane ((k&31)>>3)*16+n, sub k&7. Lane-contiguous b128 reads.
// 2 blocks x 16 batches; 8 waves (2/SIMD) x 2 row-tiles x 8 K-frags.

#define T_STEPS 8192
#define HID     240
#define CTX     180
#define KTOT    256
#define HXBUF   4096                       // halves/buffer: 8 frags x 64 lanes x 8
#define A_HALVES (256*256)
#define SCRATCH_BYTES (A_HALVES*2 + 16)

typedef __hip_bfloat16 bf16;
typedef _Float16 f16;
typedef _Float16 half8  __attribute__((ext_vector_type(8)));
typedef _Float16 half4v __attribute__((ext_vector_type(4)));
typedef float    f32x4  __attribute__((ext_vector_type(4)));
typedef float    f32x2  __attribute__((ext_vector_type(2)));

#define MFMA16(A,B,C) __builtin_amdgcn_mfma_f32_16x16x32_f16((A),(B),(C),0,0,0)

__device__ __forceinline__ float ldin(const void* p, long i, bool f32) {
    return f32 ? ((const float*)p)[i] : __bfloat162float(((const bf16*)p)[i]);
}
__device__ __forceinline__ unsigned pkbf(float a, float b) {
    unsigned ua = (unsigned)__builtin_bit_cast(unsigned short, __float2bfloat16(a));
    unsigned ub = (unsigned)__builtin_bit_cast(unsigned short, __float2bfloat16(b));
    return ua | (ub << 16);
}

// deferred out-store: writes the 6 outputs of one step (wave 7, quads 0-1)
__device__ __forceinline__ void store_out(void* out, bool f32, int quad, long ob, f32x4 v) {
    if (quad == 0) {                                   // out elems 0..3
        if (!f32) {
            bf16* op = (bf16*)out + ob;
            *(unsigned*)(op)     = pkbf(v.x, v.y);
            *(unsigned*)(op + 2) = pkbf(v.z, v.w);
        } else {
            float* op = (float*)out + ob;
            f32x2 p0 = {v.x, v.y}; *(f32x2*)(op)     = p0;
            f32x2 p1 = {v.z, v.w}; *(f32x2*)(op + 2) = p1;
        }
    } else if (quad == 1) {                            // out elems 4,5
        if (!f32) {
            bf16* op = (bf16*)out + ob;
            *(unsigned*)(op + 4) = pkbf(v.x, v.y);
        } else {
            float* op = (float*)out + ob;
            f32x2 p0 = {v.x, v.y}; *(f32x2*)(op + 4) = p0;
        }
    }
}

// fp32 arrays: low half-words are random mantissa (huge-as-bf16 w.p. ~0.45/word)
// or all-zero (bf16-grid). Real bf16 arrays: neither. (Verified R2-R10: bf16 path.)
__global__ __launch_bounds__(64) void detect_dtype(const void* data, int* flag) {
    unsigned int w  = ((const unsigned int*)data)[threadIdx.x];
    unsigned int lo = w & 0xFFFFu;
    unsigned int ex = (lo >> 7) & 0xFFu;
    unsigned long long huge = __ballot(ex >= 0x8Eu);
    unsigned long long zero = __ballot(lo == 0u);
    if (threadIdx.x == 0) *flag = (huge != 0ull || zero == ~0ull) ? 1 : 0;
}

// ---------------- build augmented A (f16) ----------------
__global__ __launch_bounds__(256) void build_A(
    const void* __restrict__ W1d, const void* __restrict__ b1d,
    const void* __restrict__ W1p, const void* __restrict__ b1p,
    const void* __restrict__ W1c, const void* __restrict__ b1c,
    const void* __restrict__ W2d, const void* __restrict__ b2d,
    const void* __restrict__ W2c, const void* __restrict__ b2c,
    f16* __restrict__ Aa, const int* __restrict__ flagp)
{
    const bool f32 = (*flagp != 0);
    int idx = blockIdx.x*256 + threadIdx.x;
    int r = idx >> 8, k = idx & 255;
    float v = 0.f;
    if (r < HID) {
        if (k < HID) {                           // M = W1c @ W2c
            float acc = 0.f;
            for (int c = 0; c < CTX; ++c)
                acc = fmaf(ldin(W1c, r*CTX+c, f32), ldin(W2c, c*HID+k, f32), acc);
            v = acc;
        } else if (k < 246) {                    // W1d columns
            v = ldin(W1d, r*6 + (k-240), f32);
        } else if (k == 246) {                   // bias: b1d+b1c+b1p + W1c@b2c
            float m0 = 0.f;
            for (int c = 0; c < CTX; ++c)
                m0 = fmaf(ldin(W1c, r*CTX+c, f32), ldin(b2c, c, f32), m0);
            v = ldin(b1d, r, f32) + ldin(b1c, r, f32) + ldin(b1p, r, f32) + m0;
        } else if (k <= 248) {                   // W1p columns
            v = ldin(W1p, r*2 + (k-247), f32);
        }
    } else if (r < 246) {                        // out rows
        int o = r - 240;
        if (k < HID)       v = ldin(W2d, o*HID + k, f32);
        else if (k == 246) v = ldin(b2d, o, f32);
    }
    Aa[idx] = (f16)v;
}

// frag-major Hx offset for scalar element (row j, col n), within one buffer
__device__ __forceinline__ int hx_off(int j, int n) {
    return (j >> 5)*512 + ((((j & 31) >> 3))*16 + n)*8 + (j & 7);
}

// ---------------- per-step MFMA recurrent kernel: 2 blocks x 16 batches ----------------
__global__ __launch_bounds__(512, 2) void rnn_mfma(
    const void* __restrict__ data,   // [30][6][8192]
    const void* __restrict__ b1d, const void* __restrict__ W1p,
    const void* __restrict__ b1p, const void* __restrict__ b1c,
    const void* __restrict__ W1d, const void* __restrict__ pb,
    const f16* __restrict__ Aa, const int* __restrict__ flagp,
    void* __restrict__ out)          // [30][8192][6]
{
    const bool f32 = (*flagp != 0);
    const int tid  = threadIdx.x;
    const int w    = __builtin_amdgcn_readfirstlane(tid >> 6);  // scalar wave id
    const int rot  = (w < 7) ? w : 0;                           // scalar K-rotation
    const int l    = tid & 63;
    const int n16  = l & 15;
    const int quad = l >> 4;
    const int base = blockIdx.x * 16;
    const int bn   = base + n16;
    const bool bvalid = (bn < 30);
    const long obase = (long)bn * T_STEPS * 6;

    __shared__ __align__(16) f16 Hx[2*HXBUF];        // 16,384 B

    // ---- zero Hx (rows >248 and untouched slots must stay 0)
    {
        int* hz = (int*)Hx;
        for (int i = tid; i < HXBUF; i += 512) hz[i] = 0;    // 4096 ints = both buffers
    }
    __syncthreads();

    // ---- const rows 246/247/248 in both buffers
    // row246 -> frag7,quad'2,j'6 ; row247 -> frag7,quad'2,j'7 ; row248 -> frag7,quad'3,j'0
    if (tid < 32) {
        int bsel = tid >> 4, n = tid & 15;
        int nb = base + n; if (nb > 29) nb = 29;
        f16* buf = Hx + bsel*HXBUF;
        buf[3584 + (32+n)*8 + 6] = (f16)1.0f;
        buf[3584 + (32+n)*8 + 7] = (f16)ldin(pb, nb*2+0, f32);
        buf[3584 + (48+n)*8 + 0] = (f16)ldin(pb, nb*2+1, f32);
    }

    // ---- h_0 = relu(cb + W1d d_0)  into Hx[0]
    for (int p = tid; p < HID*16; p += 512) {
        int n = p / HID, j = p - n*HID;
        int nb = base + n; if (nb > 29) nb = 29;
        float s = ldin(b1d, j, f32) + ldin(b1c, j, f32) + ldin(b1p, j, f32)
                + ldin(W1p, j*2+0, f32)*ldin(pb, nb*2+0, f32)
                + ldin(W1p, j*2+1, f32)*ldin(pb, nb*2+1, f32);
        for (int d = 0; d < 6; ++d)
            s = fmaf(ldin(W1d, j*6+d, f32), ldin(data, ((long)nb*6+d)*T_STEPS, f32), s);
        Hx[hx_off(j, n)] = (f16)fmaxf(s, 0.f);
    }

    // ---- d-feed lane roles (tid<96 = waves 0-1): (pn, pd)
    const int pn = tid & 15, pd = tid >> 4;
    int pnb = base + pn; if (pnb > 29) pnb = 29;
    const long prow = ((long)pnb*6 + (pd < 6 ? pd : 0))*T_STEPS;
    const int  doff = 3584 + (32+pn)*8 + pd;     // row (240+pd), col pn

    // d_1 into Hx[0] rows 240..245
    if (tid < 96)
        Hx[doff] = (f16)ldin(data, prow + 1, f32);

    // d-FIFO preload: u0 = raw d[2] (consumed step 0), u1 = raw d[3] (step 1)
    unsigned u0 = 0, u1 = 0;
    const unsigned esz = f32 ? 4u : 2u;
    unsigned voff = (unsigned)((unsigned long)(prow + 4) * esz);           // d[t+4] @ t=0
    const unsigned vmax = (unsigned)((unsigned long)(prow + T_STEPS-1) * esz);
    if (tid < 96) {
        if (!f32) {
            u0 = ((const unsigned short*)data)[prow + 2];
            u1 = ((const unsigned short*)data)[prow + 3];
        } else {
            u0 = __builtin_bit_cast(unsigned, ((const float*)data)[prow + 2]);
            u1 = __builtin_bit_cast(unsigned, ((const float*)data)[prow + 3]);
        }
    }

    // ---- persistent A fragments, PRE-ROTATED: A0r[j] = A-frag (rot+j)&7
    const f16* Ab0 = Aa + (size_t)((w*2+0)*16 + n16)*KTOT + quad*8;
    const f16* Ab1 = Aa + (size_t)((w*2+1)*16 + n16)*KTOT + quad*8;
    half8 A0r[8], A1r[8];
    #pragma unroll
    for (int j = 0; j < 8; ++j) {
        const int f = (rot + j) & 7;             // runtime addr, constexpr reg index
        A0r[j] = *(const half8*)(Ab0 + f*32);
        A1r[j] = *(const half8*)(Ab1 + f*32);
    }
    // drain A reads before any wave can store into the (possible) d_out-tail scratch
    asm volatile("s_waitcnt vmcnt(0)" ::: "memory");
    __syncthreads();

    // ---- steady-state addressing
    // rotated read pointers: rp[j] -> frag (rot+j)&7, lane-contiguous; buffer
    // select stays a compile-time imm (cur*HXBUF halves = 8192 B, fits ds imm).
    const f16* rp0 = Hx + l*8 + ((rot+0)&7)*512;
    const f16* rp1 = Hx + l*8 + ((rot+1)&7)*512;
    const f16* rp2 = Hx + l*8 + ((rot+2)&7)*512;
    const f16* rp3 = Hx + l*8 + ((rot+3)&7)*512;
    const f16* rp4 = Hx + l*8 + ((rot+4)&7)*512;
    const f16* rp5 = Hx + l*8 + ((rot+5)&7)*512;
    const f16* rp6 = Hx + l*8 + ((rot+6)&7)*512;
    const f16* rp7 = Hx + l*8 + ((rot+7)&7)*512;
    // write: tile 2w at off0, tile 2w+1 at off0+256 (buffer select = +nxt*HXBUF)
    f16* hxw = Hx + w*512 + ((quad>>1)*16 + n16)*8 + 4*(quad&1);

    f32x4 pend = {0.f, 0.f, 0.f, 0.f};           // wave7: out values awaiting store
    half8 b_e = *(const half8*)(rp0);            // pre-loop: own/first frag of buf[0]

    for (int t2 = 0; t2 < T_STEPS; t2 += 2) {
        #pragma unroll
        for (int s = 0; s < 2; ++s) {
            const int t = t2 + s;
            const int cur = s, nxt = s ^ 1;      // compile-time parity

            // ---- (1) B frags: b0 register-resident (w<7); issue the other 7 reads
            half8 b0, b1, b2, b3, b4, b5, b6, b7;
            if (w < 7) b0 = b_e;
            else       b0 = *(const half8*)(rp0 + cur*HXBUF);
            b1 = *(const half8*)(rp1 + cur*HXBUF);
            b2 = *(const half8*)(rp2 + cur*HXBUF);
            b3 = *(const half8*)(rp3 + cur*HXBUF);
            b4 = *(const half8*)(rp4 + cur*HXBUF);
            b5 = *(const half8*)(rp5 + cur*HXBUF);
            b6 = *(const half8*)(rp6 + cur*HXBUF);
            b7 = *(const half8*)(rp7 + cur*HXBUF);

            // ---- (2) bubble fill: deferred out-store for step t-1 (wave 7)
            if (w == 7 && bvalid && (s == 1 || t2 > 0))
                store_out(out, f32, quad, obase + (long)(t-1)*6, pend);

            // ---- bubble fill: d-feed (waves 0-1): d_{t+2} -> Hx[nxt]; load d[t+4]
            if (tid < 96) {
                unsigned uc = (s == 0) ? u0 : u1;
                float dv = f32 ? __builtin_bit_cast(float, uc)
                               : __builtin_bit_cast(float, uc << 16);
                Hx[nxt*HXBUF + doff] = (f16)dv;
                unsigned un;
                if (!f32) un = *(const unsigned short*)((const char*)data + voff);
                else      un = __builtin_bit_cast(unsigned, *(const float*)((const char*)data + voff));
                unsigned vn = voff + esz;
                voff = (vn > vmax) ? vmax : vn;
                if (s == 0) u0 = un; else u1 = un;
            }

            // ---- (3) MFMA chains (uniform body; rotation is in the data)
            f32x4 c0 = {0.f,0.f,0.f,0.f}, c1 = {0.f,0.f,0.f,0.f};
            c0 = MFMA16(A0r[0], b0, c0);
            c1 = MFMA16(A1r[1], b1, c1);
            c0 = MFMA16(A0r[1], b1, c0);
            c1 = MFMA16(A1r[2], b2, c1);
            c0 = MFMA16(A0r[2], b2, c0);
            c1 = MFMA16(A1r[3], b3, c1);
            c0 = MFMA16(A0r[3], b3, c0);
            c1 = MFMA16(A1r[4], b4, c1);
            c0 = MFMA16(A0r[4], b4, c0);
            c1 = MFMA16(A1r[5], b5, c1);
            c0 = MFMA16(A0r[5], b5, c0);
            c1 = MFMA16(A1r[6], b6, c1);
            c0 = MFMA16(A0r[6], b6, c0);
            c1 = MFMA16(A1r[7], b7, c1);
            c0 = MFMA16(A0r[7], b7, c0);

            // ---- epilogue c0 (tile 2w, always h): overlaps c1's last MFMA
            f16* hxn = hxw + nxt*HXBUF;
            {
                half4v hv;
                hv.x = (f16)fmaxf(c0.x, 0.f);
                hv.y = (f16)fmaxf(c0.y, 0.f);
                hv.z = (f16)fmaxf(c0.z, 0.f);
                hv.w = (f16)fmaxf(c0.w, 0.f);
                *(half4v*)(hxn) = hv;
            }
            c1 = MFMA16(A1r[0], b0, c1);         // c1's final (rotated) MFMA

            // ---- epilogue c1: h-tile for waves 0-6; wave 7 defers out to t+1
            if (w < 7) {                         // tile 2w+1: h-tile
                half4v hv;
                hv.x = (f16)fmaxf(c1.x, 0.f);
                hv.y = (f16)fmaxf(c1.y, 0.f);
                hv.z = (f16)fmaxf(c1.z, 0.f);
                hv.w = (f16)fmaxf(c1.w, 0.f);
                *(half4v*)(hxn + 256) = hv;
            } else {
                pend = c1;                       // stored in next step's bubble
            }

            // ---- tail: drain my LDS writes; EARLY-READ own frag of buf[nxt]
            // (legal for w<7: frag w = rows [32w,32w+32) are exactly MY h-writes,
            // drained by lgkmcnt(0)); then barrier. Read completes in the
            // barrier-wait shadow and becomes b0 next step.
            asm volatile("s_waitcnt lgkmcnt(0)" ::: "memory");
            if (w < 7)
                b_e = *(const half8*)(rp0 + nxt*HXBUF);
            asm volatile("s_barrier" ::: "memory");
        }
    }

    // ---- final flush: out for t = T_STEPS-1
    if (w == 7 && bvalid)
        store_out(out, f32, quad, obase + (long)(T_STEPS-1)*6, pend);
}

extern "C" void kernel_launch(void* const* d_in, const int* in_sizes, int n_in,
                              void* d_out, int out_size, void* d_ws, size_t ws_size,
                              hipStream_t stream) {
    const void* data = d_in[0];
    const void* W1d  = d_in[1];
    const void* b1d  = d_in[2];
    const void* W1p  = d_in[3];
    const void* b1p  = d_in[4];
    const void* W1c  = d_in[5];
    const void* b1c  = d_in[6];
    const void* W2d  = d_in[7];
    const void* b2d  = d_in[8];
    const void* W2c  = d_in[9];
    const void* b2c  = d_in[10];
    const void* pb   = d_in[11];

    size_t need = SCRATCH_BYTES;
    char* scratch;
    if (ws_size >= need) {
        scratch = (char*)d_ws;
    } else {
        size_t out_bytes = (size_t)30*T_STEPS*6*sizeof(bf16);
        scratch = (char*)d_out + ((out_bytes - need) & ~(size_t)255);
    }
    f16* Aa    = (f16*)scratch;
    int* flagp = (int*)(scratch + A_HALVES*2);

    detect_dtype<<<1, 64, 0, stream>>>(data, flagp);
    build_A<<<A_HALVES/256, 256, 0, stream>>>(W1d, b1d, W1p, b1p, W1c, b1c,
                                              W2d, b2d, W2c, b2c, Aa, flagp);
    rnn_mfma<<<2, 512, 0, stream>>>(data, b1d, W1p, b1p, b1c, W1d, pb,
                                    Aa, flagp, d_out);
}

// Round 7
// 3655.610 us; speedup vs baseline: 1.4281x; 1.0343x over previous
//
#include <hip/hip_runtime.h>
#include <hip/hip_bf16.h>
#include <stdint.h>

// RNNPB via per-step MFMA GEMM (R18 = revert to R15, the empirical optimum).
// Post-R17 accounting (normalized to the 2 active CUs): MFMA pipe ~49% busy
// = 515 cyc/step/SIMD (32 MFMA x 16.1 cyc = peak-rate issue) -- the tall pole.
// LDS pipe is only ~100-120 cyc/step aggregate (8KB reads @128B/cyc/CU).
// Residual ~530 cyc/step = recurrence-serial latency (barrier + LDS write->
// read round-trip + chain fill/drain + epilogue VALU sharing issue with MFMA).
// Attacks on the residual: R12 (fewer waves) -9%, R13 (conflict-free layout)
// neutral, R14 (K-split exchange) -45%, R15 (reads-first + bubble-fill +
// deferred out-store) +8% WIN, R16 (code-rotated chains) -31% (I-cache),
// R17 (data-rotated + own-frag early-read) -4% (1/8-frag prefetch < overhead).
// -> R15 is the floor of this structure; this round restores it verbatim.
//   h_{t+1} = relu(M h_t + W1d d_{t+1} + cb' + W1p pb),  out_t = W2d h_t + b2d
// A (f16, 256x256): rows [0,240) h, [240,246) out (W2d); cols [0,240) M/W2d,
//   [240,246) W1d, 246 bias, 247/248 W1p, 249+ zero.
// B panel frag-major: Hx[buf][frag 0..7][lane 0..63][8 halves]; element (k,n):
//   frag k>>5, lane ((k&31)>>3)*16+n, sub k&7.  Lane-contiguous b128 reads
//   (conflict-free); h-writes are one b64 per lane.
// 2 blocks x 16 batches; 8 waves (2/SIMD) x 2 row-tiles x 8 K-frags.
// d-input via 96-lane register FIFO (waves 0-1): one 2B L2-hot load per step.

#define T_STEPS 8192
#define HID     240
#define CTX     180
#define KTOT    256
#define HXBUF   4096                       // halves/buffer: 8 frags x 64 lanes x 8
#define A_HALVES (256*256)
#define SCRATCH_BYTES (A_HALVES*2 + 16)

typedef __hip_bfloat16 bf16;
typedef _Float16 f16;
typedef _Float16 half8  __attribute__((ext_vector_type(8)));
typedef _Float16 half4v __attribute__((ext_vector_type(4)));
typedef float    f32x4  __attribute__((ext_vector_type(4)));
typedef float    f32x2  __attribute__((ext_vector_type(2)));

#define MFMA16(A,B,C) __builtin_amdgcn_mfma_f32_16x16x32_f16((A),(B),(C),0,0,0)

__device__ __forceinline__ float ldin(const void* p, long i, bool f32) {
    return f32 ? ((const float*)p)[i] : __bfloat162float(((const bf16*)p)[i]);
}
__device__ __forceinline__ unsigned pkbf(float a, float b) {
    unsigned ua = (unsigned)__builtin_bit_cast(unsigned short, __float2bfloat16(a));
    unsigned ub = (unsigned)__builtin_bit_cast(unsigned short, __float2bfloat16(b));
    return ua | (ub << 16);
}
// LDS-ordering barrier WITHOUT vmem drain (out-stores/d-loads stay in flight)
__device__ __forceinline__ void barrier_lds() {
    asm volatile("s_waitcnt lgkmcnt(0)\n\ts_barrier" ::: "memory");
}

// deferred out-store: writes the 6 outputs of one step (wave 7, quads 0-1)
__device__ __forceinline__ void store_out(void* out, bool f32, int quad, long ob, f32x4 v) {
    if (quad == 0) {                                   // out elems 0..3
        if (!f32) {
            bf16* op = (bf16*)out + ob;
            *(unsigned*)(op)     = pkbf(v.x, v.y);
            *(unsigned*)(op + 2) = pkbf(v.z, v.w);
        } else {
            float* op = (float*)out + ob;
            f32x2 p0 = {v.x, v.y}; *(f32x2*)(op)     = p0;
            f32x2 p1 = {v.z, v.w}; *(f32x2*)(op + 2) = p1;
        }
    } else if (quad == 1) {                            // out elems 4,5
        if (!f32) {
            bf16* op = (bf16*)out + ob;
            *(unsigned*)(op + 4) = pkbf(v.x, v.y);
        } else {
            float* op = (float*)out + ob;
            f32x2 p0 = {v.x, v.y}; *(f32x2*)(op + 4) = p0;
        }
    }
}

// fp32 arrays: low half-words are random mantissa (huge-as-bf16 w.p. ~0.45/word)
// or all-zero (bf16-grid). Real bf16 arrays: neither. (Verified R2-R10: bf16 path.)
__global__ __launch_bounds__(64) void detect_dtype(const void* data, int* flag) {
    unsigned int w  = ((const unsigned int*)data)[threadIdx.x];
    unsigned int lo = w & 0xFFFFu;
    unsigned int ex = (lo >> 7) & 0xFFu;
    unsigned long long huge = __ballot(ex >= 0x8Eu);
    unsigned long long zero = __ballot(lo == 0u);
    if (threadIdx.x == 0) *flag = (huge != 0ull || zero == ~0ull) ? 1 : 0;
}

// ---------------- build augmented A (f16) ----------------
__global__ __launch_bounds__(256) void build_A(
    const void* __restrict__ W1d, const void* __restrict__ b1d,
    const void* __restrict__ W1p, const void* __restrict__ b1p,
    const void* __restrict__ W1c, const void* __restrict__ b1c,
    const void* __restrict__ W2d, const void* __restrict__ b2d,
    const void* __restrict__ W2c, const void* __restrict__ b2c,
    f16* __restrict__ Aa, const int* __restrict__ flagp)
{
    const bool f32 = (*flagp != 0);
    int idx = blockIdx.x*256 + threadIdx.x;
    int r = idx >> 8, k = idx & 255;
    float v = 0.f;
    if (r < HID) {
        if (k < HID) {                           // M = W1c @ W2c
            float acc = 0.f;
            for (int c = 0; c < CTX; ++c)
                acc = fmaf(ldin(W1c, r*CTX+c, f32), ldin(W2c, c*HID+k, f32), acc);
            v = acc;
        } else if (k < 246) {                    // W1d columns
            v = ldin(W1d, r*6 + (k-240), f32);
        } else if (k == 246) {                   // bias: b1d+b1c+b1p + W1c@b2c
            float m0 = 0.f;
            for (int c = 0; c < CTX; ++c)
                m0 = fmaf(ldin(W1c, r*CTX+c, f32), ldin(b2c, c, f32), m0);
            v = ldin(b1d, r, f32) + ldin(b1c, r, f32) + ldin(b1p, r, f32) + m0;
        } else if (k <= 248) {                   // W1p columns
            v = ldin(W1p, r*2 + (k-247), f32);
        }
    } else if (r < 246) {                        // out rows
        int o = r - 240;
        if (k < HID)       v = ldin(W2d, o*HID + k, f32);
        else if (k == 246) v = ldin(b2d, o, f32);
    }
    Aa[idx] = (f16)v;
}

// frag-major Hx offset for scalar element (row j, col n), within one buffer
__device__ __forceinline__ int hx_off(int j, int n) {
    return (j >> 5)*512 + ((((j & 31) >> 3))*16 + n)*8 + (j & 7);
}

// ---------------- per-step MFMA recurrent kernel: 2 blocks x 16 batches ----------------
__global__ __launch_bounds__(512, 2) void rnn_mfma(
    const void* __restrict__ data,   // [30][6][8192]
    const void* __restrict__ b1d, const void* __restrict__ W1p,
    const void* __restrict__ b1p, const void* __restrict__ b1c,
    const void* __restrict__ W1d, const void* __restrict__ pb,
    const f16* __restrict__ Aa, const int* __restrict__ flagp,
    void* __restrict__ out)          // [30][8192][6]
{
    const bool f32 = (*flagp != 0);
    const int tid  = threadIdx.x;
    const int w    = tid >> 6;       // wave 0..7: row-tiles {2w, 2w+1}; wave7 tile15 = out
    const int l    = tid & 63;
    const int n16  = l & 15;
    const int quad = l >> 4;
    const int base = blockIdx.x * 16;
    const int bn   = base + n16;
    const bool bvalid = (bn < 30);
    const long obase = (long)bn * T_STEPS * 6;

    __shared__ __align__(16) f16 Hx[2*HXBUF];        // 16,384 B

    // ---- zero Hx (rows >248 and untouched slots must stay 0)
    {
        int* hz = (int*)Hx;
        for (int i = tid; i < HXBUF; i += 512) hz[i] = 0;    // 4096 ints = both buffers
    }
    __syncthreads();

    // ---- const rows 246/247/248 in both buffers
    // row246 -> frag7,quad'2,j'6 ; row247 -> frag7,quad'2,j'7 ; row248 -> frag7,quad'3,j'0
    if (tid < 32) {
        int bsel = tid >> 4, n = tid & 15;
        int nb = base + n; if (nb > 29) nb = 29;
        f16* buf = Hx + bsel*HXBUF;
        buf[3584 + (32+n)*8 + 6] = (f16)1.0f;
        buf[3584 + (32+n)*8 + 7] = (f16)ldin(pb, nb*2+0, f32);
        buf[3584 + (48+n)*8 + 0] = (f16)ldin(pb, nb*2+1, f32);
    }

    // ---- h_0 = relu(cb + W1d d_0)  into Hx[0]
    for (int p = tid; p < HID*16; p += 512) {
        int n = p / HID, j = p - n*HID;
        int nb = base + n; if (nb > 29) nb = 29;
        float s = ldin(b1d, j, f32) + ldin(b1c, j, f32) + ldin(b1p, j, f32)
                + ldin(W1p, j*2+0, f32)*ldin(pb, nb*2+0, f32)
                + ldin(W1p, j*2+1, f32)*ldin(pb, nb*2+1, f32);
        for (int d = 0; d < 6; ++d)
            s = fmaf(ldin(W1d, j*6+d, f32), ldin(data, ((long)nb*6+d)*T_STEPS, f32), s);
        Hx[hx_off(j, n)] = (f16)fmaxf(s, 0.f);
    }

    // ---- d-feed lane roles (tid<96 = waves 0-1): (pn, pd)
    const int pn = tid & 15, pd = tid >> 4;
    int pnb = base + pn; if (pnb > 29) pnb = 29;
    const long prow = ((long)pnb*6 + (pd < 6 ? pd : 0))*T_STEPS;
    const int  doff = 3584 + (32+pn)*8 + pd;     // row (240+pd), col pn

    // d_1 into Hx[0] rows 240..245
    if (tid < 96)
        Hx[doff] = (f16)ldin(data, prow + 1, f32);

    // d-FIFO preload: u0 = raw d[2] (consumed step 0), u1 = raw d[3] (step 1)
    unsigned u0 = 0, u1 = 0;
    const unsigned esz = f32 ? 4u : 2u;
    unsigned voff = (unsigned)((unsigned long)(prow + 4) * esz);           // d[t+4] @ t=0
    const unsigned vmax = (unsigned)((unsigned long)(prow + T_STEPS-1) * esz);
    if (tid < 96) {
        if (!f32) {
            u0 = ((const unsigned short*)data)[prow + 2];
            u1 = ((const unsigned short*)data)[prow + 3];
        } else {
            u0 = __builtin_bit_cast(unsigned, ((const float*)data)[prow + 2]);
            u1 = __builtin_bit_cast(unsigned, ((const float*)data)[prow + 3]);
        }
    }

    // ---- persistent A fragments: 16 NAMED half8 locals (AGPR-resident)
    const f16* Ab0 = Aa + (size_t)((w*2+0)*16 + n16)*KTOT + quad*8;
    const f16* Ab1 = Aa + (size_t)((w*2+1)*16 + n16)*KTOT + quad*8;
    half8 a00 = *(const half8*)(Ab0 +   0), a01 = *(const half8*)(Ab0 +  32);
    half8 a02 = *(const half8*)(Ab0 +  64), a03 = *(const half8*)(Ab0 +  96);
    half8 a04 = *(const half8*)(Ab0 + 128), a05 = *(const half8*)(Ab0 + 160);
    half8 a06 = *(const half8*)(Ab0 + 192), a07 = *(const half8*)(Ab0 + 224);
    half8 a10 = *(const half8*)(Ab1 +   0), a11 = *(const half8*)(Ab1 +  32);
    half8 a12 = *(const half8*)(Ab1 +  64), a13 = *(const half8*)(Ab1 +  96);
    half8 a14 = *(const half8*)(Ab1 + 128), a15 = *(const half8*)(Ab1 + 160);
    half8 a16 = *(const half8*)(Ab1 + 192), a17 = *(const half8*)(Ab1 + 224);
    // drain A reads before any wave can store into the (possible) d_out-tail scratch
    asm volatile("s_waitcnt vmcnt(0)" ::: "memory");
    __syncthreads();

    // ---- steady-state addressing
    // read: lane-contiguous; cur/frag are compile-time imm offsets
    const f16* hxread0 = Hx + l*8;
    // write: tile 2w at off0, tile 2w+1 at off0+256 (buffer select = +nxt*HXBUF)
    f16* hxw = Hx + w*512 + ((quad>>1)*16 + n16)*8 + 4*(quad&1);

    f32x4 pend = {0.f, 0.f, 0.f, 0.f};           // wave7: out values awaiting store

    for (int t2 = 0; t2 < T_STEPS; t2 += 2) {
        #pragma unroll
        for (int s = 0; s < 2; ++s) {
            const int t = t2 + s;
            const int cur = s, nxt = s ^ 1;      // compile-time parity

            // ---- (1) B fragment reads FIRST: start the LDS-pipe drain at once
            const f16* hxc = hxread0 + cur*HXBUF;
            half8 b0 = *(const half8*)(hxc +    0);
            half8 b1 = *(const half8*)(hxc +  512);
            half8 b2 = *(const half8*)(hxc + 1024);
            half8 b3 = *(const half8*)(hxc + 1536);
            half8 b4 = *(const half8*)(hxc + 2048);
            half8 b5 = *(const half8*)(hxc + 2560);
            half8 b6 = *(const half8*)(hxc + 3072);
            half8 b7 = *(const half8*)(hxc + 3584);

            // ---- (2) bubble fill: deferred out-store for step t-1 (wave 7)
            if (w == 7 && bvalid && (s == 1 || t2 > 0))
                store_out(out, f32, quad, obase + (long)(t-1)*6, pend);

            // ---- bubble fill: d-feed (waves 0-1): d_{t+2} -> Hx[nxt]; load d[t+4]
            if (tid < 96) {
                unsigned uc = (s == 0) ? u0 : u1;
                float dv = f32 ? __builtin_bit_cast(float, uc)
                               : __builtin_bit_cast(float, uc << 16);
                Hx[nxt*HXBUF + doff] = (f16)dv;
                unsigned un;
                if (!f32) un = *(const unsigned short*)((const char*)data + voff);
                else      un = __builtin_bit_cast(unsigned, *(const float*)((const char*)data + voff));
                unsigned vn = voff + esz;
                voff = (vn > vmax) ? vmax : vn;
                if (s == 0) u0 = un; else u1 = un;
            }

            // ---- (3) MFMA: c0 frags 0..7, c1 rotated 1..7,0 (c0 finishes early)
            f32x4 c0 = {0.f,0.f,0.f,0.f}, c1 = {0.f,0.f,0.f,0.f};
            c0 = MFMA16(a00, b0, c0);
            c1 = MFMA16(a11, b1, c1);
            c0 = MFMA16(a01, b1, c0);
            c1 = MFMA16(a12, b2, c1);
            c0 = MFMA16(a02, b2, c0);
            c1 = MFMA16(a13, b3, c1);
            c0 = MFMA16(a03, b3, c0);
            c1 = MFMA16(a14, b4, c1);
            c0 = MFMA16(a04, b4, c0);
            c1 = MFMA16(a15, b5, c1);
            c0 = MFMA16(a05, b5, c0);
            c1 = MFMA16(a16, b6, c1);
            c0 = MFMA16(a06, b6, c0);
            c1 = MFMA16(a17, b7, c1);
            c0 = MFMA16(a07, b7, c0);

            // ---- epilogue c0 (tile 2w, always h): overlaps c1's last MFMA
            f16* hxn = hxw + nxt*HXBUF;
            {
                half4v hv;
                hv.x = (f16)fmaxf(c0.x, 0.f);
                hv.y = (f16)fmaxf(c0.y, 0.f);
                hv.z = (f16)fmaxf(c0.z, 0.f);
                hv.w = (f16)fmaxf(c0.w, 0.f);
                *(half4v*)(hxn) = hv;
            }
            c1 = MFMA16(a10, b0, c1);            // c1's final (rotated) MFMA

            // ---- epilogue c1: h-tile for waves 0-6; wave 7 defers out to t+1
            if (w < 7) {                         // tile 2w+1: h-tile
                half4v hv;
                hv.x = (f16)fmaxf(c1.x, 0.f);
                hv.y = (f16)fmaxf(c1.y, 0.f);
                hv.z = (f16)fmaxf(c1.z, 0.f);
                hv.w = (f16)fmaxf(c1.w, 0.f);
                *(half4v*)(hxn + 256) = hv;
            } else {
                pend = c1;                       // stored in next step's bubble
            }
            barrier_lds();                       // lgkmcnt only -- vmem stays in flight
        }
    }

    // ---- final flush: out for t = T_STEPS-1
    if (w == 7 && bvalid)
        store_out(out, f32, quad, obase + (long)(T_STEPS-1)*6, pend);
}

extern "C" void kernel_launch(void* const* d_in, const int* in_sizes, int n_in,
                              void* d_out, int out_size, void* d_ws, size_t ws_size,
                              hipStream_t stream) {
    const void* data = d_in[0];
    const void* W1d  = d_in[1];
    const void* b1d  = d_in[2];
    const void* W1p  = d_in[3];
    const void* b1p  = d_in[4];
    const void* W1c  = d_in[5];
    const void* b1c  = d_in[6];
    const void* W2d  = d_in[7];
    const void* b2d  = d_in[8];
    const void* W2c  = d_in[9];
    const void* b2c  = d_in[10];
    const void* pb   = d_in[11];

    size_t need = SCRATCH_BYTES;
    char* scratch;
    if (ws_size >= need) {
        scratch = (char*)d_ws;
    } else {
        size_t out_bytes = (size_t)30*T_STEPS*6*sizeof(bf16);
        scratch = (char*)d_out + ((out_bytes - need) & ~(size_t)255);
    }
    f16* Aa    = (f16*)scratch;
    int* flagp = (int*)(scratch + A_HALVES*2);

    detect_dtype<<<1, 64, 0, stream>>>(data, flagp);
    build_A<<<A_HALVES/256, 256, 0, stream>>>(W1d, b1d, W1p, b1p, W1c, b1c,
                                              W2d, b2d, W2c, b2c, Aa, flagp);
    rnn_mfma<<<2, 512, 0, stream>>>(data, b1d, W1p, b1p, b1c, W1d, pb,
                                    Aa, flagp, d_out);
}